// Round 4
// baseline (748.692 us; speedup 1.0000x reference)
//
#include <hip/hip_runtime.h>
#include <math.h>

// Problem constants
#define B_    32
#define H_IN  161
#define W_IN  1024
#define C1_   32
#define H1_   81
#define W1_   512
#define C2_   32
#define H2_   41
#define W2_   512

#define OUT_X_SZ ((size_t)B_ * C2_ * H2_ * W2_)            // 21,495,808

// ws byte offsets (all 16B-aligned)
#define WF2_B    0u            // 236544 bf16 (conv2 weights, A-frag order)
#define WF1_B    473088u       // 41*512 bf16 (conv1 weights, A-frag order, k 11->16 zero-pad)
#define SCSH_B   515072u       // 128 fp32
#define LENS1_B  515584u       // 32 int
#define XBF_B    515712u       // 32*161*1048 bf16 padded input = 10,798,592 B
#define XG_B     11314304u     // 32*81*512*32 bf16 = 84,934,656 B

#define WF2_N    236544
#define WF1_N    20992         // 41 * 512
#define XBF_ROW  1048          // slots per padded row; slot = col + 5
#define XBF_N    (32 * 161 * XBF_ROW)

typedef __bf16 v8bf __attribute__((ext_vector_type(8)));
typedef float v16f __attribute__((ext_vector_type(16)));

static __device__ __forceinline__ unsigned short f2bf(float f) {
    unsigned int u = __float_as_uint(f);
    unsigned int r = (u + 0x7fffu + ((u >> 16) & 1u)) >> 16;
    return (unsigned short)r;
}

// ---------------------------------------------------------------------------
// Prep: pack weights to MFMA A-frag order, fold BN, compute lens, and convert
// input to zero-padded bf16 rows (slot = col+5 so fragment starts are 4B-aligned).
// ---------------------------------------------------------------------------
__global__ void prep_kernel(const float* __restrict__ x,
                            const float* __restrict__ w1, const float* __restrict__ b1,
                            const float* __restrict__ g1, const float* __restrict__ be1,
                            const float* __restrict__ m1, const float* __restrict__ v1,
                            const float* __restrict__ w2, const float* __restrict__ b2,
                            const float* __restrict__ g2, const float* __restrict__ be2,
                            const float* __restrict__ m2, const float* __restrict__ v2,
                            const int* __restrict__ lens,
                            unsigned short* __restrict__ wf1, unsigned short* __restrict__ wf2,
                            unsigned short* __restrict__ xbf,
                            float* __restrict__ scsh, int* __restrict__ lens1,
                            float* __restrict__ out_lens)
{
    const int i = blockIdx.x * blockDim.x + threadIdx.x;
    const int stride = gridDim.x * blockDim.x;

    // padded bf16 input
    for (int idx = i; idx < XBF_N; idx += stride) {
        int s  = idx % XBF_ROW;
        int br = idx / XBF_ROW;          // b*161 + r
        int c  = s - 5;
        float v = 0.f;
        if ((unsigned)c < (unsigned)W_IN) v = x[(size_t)br * W_IN + c];
        xbf[idx] = f2bf(v);
    }
    // wf2: frag f=(kh*11+kw)*2+ch, lane l, elem j <- w2[oc=l&31][c=ch*16+(l>>5)*8+j][kh][kw]
    for (int idx = i; idx < WF2_N; idx += stride) {
        int j  = idx & 7;
        int l  = (idx >> 3) & 63;
        int f  = idx >> 9;
        int ch = f & 1;
        int kwkh = f >> 1;
        int kw = kwkh % 11;
        int kh = kwkh / 11;
        int oc = l & 31;
        int c  = ch * 16 + ((l >> 5) << 3) + j;
        wf2[idx] = f2bf(w2[((oc * 32 + c) * 21 + kh) * 11 + kw]);
    }
    // wf1: frag kh, lane l, elem j <- w1[oc=l&31][kh][k=(l>>5)*8+j], zero for k>=11
    for (int idx = i; idx < WF1_N; idx += stride) {
        int j  = idx & 7;
        int l  = (idx >> 3) & 63;
        int kh = idx >> 9;
        int k  = ((l >> 5) << 3) + j;
        int oc = l & 31;
        wf1[idx] = (k < 11) ? f2bf(w1[oc * 451 + kh * 11 + k]) : (unsigned short)0;
    }
    if (i < 32) {
        float s1 = g1[i] / sqrtf(v1[i] + 1e-5f);
        scsh[i]      = s1;
        scsh[32 + i] = b1[i] * s1 + be1[i] - m1[i] * s1;
        float s2 = g2[i] / sqrtf(v2[i] + 1e-5f);
        scsh[64 + i] = s2;
        scsh[96 + i] = b2[i] * s2 + be2[i] - m2[i] * s2;
        int l1 = (lens[i] - 1) / 2 + 1;
        if (l1 > W1_) l1 = W1_;
        lens1[i] = l1;
        out_lens[i] = (float)l1;
    }
}

// ---------------------------------------------------------------------------
// Conv1 MFMA, no LDS, no barriers. Block = 128 w x 4 h; each wave owns 32 w.
// Per input row: 1 B-frag (global, L1-hot) shared by up to 4 hh MFMAs.
// ---------------------------------------------------------------------------
__global__ __launch_bounds__(256) void conv1_mfma(
    const unsigned short* __restrict__ xbf,  // [32][161][1048] padded bf16
    const unsigned short* __restrict__ wf1,
    const float* __restrict__ scsh,
    const int* __restrict__ lens1,
    unsigned short* __restrict__ xg)         // [32][81][512][32] bf16
{
    const int t    = threadIdx.x;
    const int lane = t & 63;
    const int l31  = lane & 31;
    const int lhi  = lane >> 5;
    const int wv   = t >> 6;
    const int W    = blockIdx.x * 128 + wv * 32;
    const int h0   = blockIdx.y * 4;
    const int b    = blockIdx.z;

    v16f acc[4];
#pragma unroll
    for (int hh = 0; hh < 4; ++hh)
#pragma unroll
        for (int i = 0; i < 16; ++i) acc[hh][i] = 0.f;

    const char* xrow0 = (const char*)(xbf + (size_t)b * (H_IN * XBF_ROW));
    // fragment byte offset within a row: slot = 2*(W+l31) + 8*lhi, byte = 2*slot
    const int boff = 4 * (W + l31) + 16 * lhi;

    for (int rr = 0; rr < 47; ++rr) {
        const int r = 2 * h0 - 20 + rr;
        if (r < 0 || r >= H_IN) continue;

        const unsigned int* bp = (const unsigned int*)(xrow0 + (size_t)r * (XBF_ROW * 2) + boff);
        uint4 bu; bu.x = bp[0]; bu.y = bp[1]; bu.z = bp[2]; bu.w = bp[3];
        v8bf bv = __builtin_bit_cast(v8bf, bu);

#pragma unroll
        for (int hh = 0; hh < 4; ++hh) {
            const int kh = rr - 2 * hh;
            if ((unsigned)kh < 41u && (h0 + hh) < H1_) {
                uint4 au = *((const uint4*)wf1 + kh * 64 + lane);
                acc[hh] = __builtin_amdgcn_mfma_f32_32x32x16_bf16(
                    __builtin_bit_cast(v8bf, au), bv, acc[hh], 0, 0, 0);
            }
        }
    }

    // epilogue: BN + hardtanh + mask, write xg[b][h][w][c] bf16
    const int l1 = lens1[b];
    const int w  = W + l31;
    const bool keep = (w < l1);
#pragma unroll
    for (int hh = 0; hh < 4; ++hh) {
        const int h = h0 + hh;
        if (h < H1_) {
            unsigned short* dp = xg + (((size_t)b * H1_ + h) * W1_ + w) * 32;
#pragma unroll
            for (int rq = 0; rq < 4; ++rq) {
                unsigned int wd[2];
#pragma unroll
                for (int d = 0; d < 2; ++d) {
                    int rg = rq * 4 + d * 2;
                    int oc = 8 * rq + 4 * lhi + d * 2;
                    float v0 = fminf(fmaxf(fmaf(acc[hh][rg],     scsh[oc],     scsh[32 + oc]), 0.f), 20.f);
                    float v1 = fminf(fmaxf(fmaf(acc[hh][rg + 1], scsh[oc + 1], scsh[33 + oc]), 0.f), 20.f);
                    if (!keep) { v0 = 0.f; v1 = 0.f; }
                    wd[d] = (unsigned int)f2bf(v0) | ((unsigned int)f2bf(v1) << 16);
                }
                uint2 u; u.x = wd[0]; u.y = wd[1];
                *(uint2*)(dp + 8 * rq + 4 * lhi) = u;
            }
        }
    }
}

// ---------------------------------------------------------------------------
// Conv2 MFMA with h-blocking (Hb=4). Block = 128 w x 4 h; 1 n-tile per wave.
// Per input row: 22 B-frag LDS reads shared by up to 88 MFMAs (4 hh each).
// LDS: row of 138 w-slots x 80B stride, double-buffered.
// ---------------------------------------------------------------------------
#define ROWB2 11040   // 138 * 80

__global__ __launch_bounds__(256, 3) void conv2_mfma(
    const unsigned short* __restrict__ xg,   // [32][81][512][32] bf16
    const unsigned short* __restrict__ wf2,  // frag-ordered
    const float* __restrict__ scsh,
    const int* __restrict__ lens1,
    float* __restrict__ out)                 // [32][32][41][512] fp32
{
    const int t    = threadIdx.x;
    const int lane = t & 63;
    const int l31  = lane & 31;
    const int lhi  = lane >> 5;
    const int wv   = t >> 6;
    const int w0   = blockIdx.x * 128;
    const int h0   = blockIdx.y * 4;
    const int b    = blockIdx.z;

    __shared__ __align__(16) char sbuf[2 * ROWB2];

    v16f acc[4];
#pragma unroll
    for (int hh = 0; hh < 4; ++hh)
#pragma unroll
        for (int i = 0; i < 16; ++i) acc[hh][i] = 0.f;

    // staging: 552 uint4 chunks (138 w-slots x 4), thread t handles i = t, t+256, t+512(<552)
    const int i1 = t + 256, i2 = t + 512;
    const int st0 = (t >> 2) * 80 + (t & 3) * 16;
    const int st1 = (i1 >> 2) * 80 + (i1 & 3) * 16;
    const int st2 = (i2 >> 2) * 80 + (i2 & 3) * 16;
    const int gw0 = w0 - 5 + (t >> 2);
    const int gw1 = w0 - 5 + (i1 >> 2);
    const int gw2 = w0 - 5 + (i2 >> 2);
    const int gc0 = (t & 3) * 8, gc1 = (i1 & 3) * 8, gc2 = (i2 & 3) * 8;

    const unsigned short* xb = xg + (size_t)b * (H1_ * W1_ * 32);
    const int rbase = 2 * h0 - 10;

    // prologue: stage row rbase into buffer 0
    if (rbase >= 0 && rbase < H1_) {
        const unsigned short* xr = xb + (size_t)rbase * (W1_ * 32);
        uint4 z0 = {0,0,0,0}, z1 = {0,0,0,0}, z2 = {0,0,0,0};
        if ((unsigned)gw0 < (unsigned)W1_) z0 = *(const uint4*)(xr + (size_t)gw0 * 32 + gc0);
        if ((unsigned)gw1 < (unsigned)W1_) z1 = *(const uint4*)(xr + (size_t)gw1 * 32 + gc1);
        if (t < 40 && (unsigned)gw2 < (unsigned)W1_) z2 = *(const uint4*)(xr + (size_t)gw2 * 32 + gc2);
        *(uint4*)(sbuf + st0) = z0;
        *(uint4*)(sbuf + st1) = z1;
        if (t < 40) *(uint4*)(sbuf + st2) = z2;
    }
    __syncthreads();

    const int bro = (wv * 32 + l31) * 80 + lhi * 16;   // + kw*80 + ch*32

    for (int rr = 0; rr < 27; ++rr) {
        const int p  = rr & 1;
        const int rn = rbase + rr + 1;
        const bool sv = (rr < 26) && rn >= 0 && rn < H1_;

        uint4 z0 = {0,0,0,0}, z1 = {0,0,0,0}, z2 = {0,0,0,0};
        if (sv) {
            const unsigned short* xr = xb + (size_t)rn * (W1_ * 32);
            if ((unsigned)gw0 < (unsigned)W1_) z0 = *(const uint4*)(xr + (size_t)gw0 * 32 + gc0);
            if ((unsigned)gw1 < (unsigned)W1_) z1 = *(const uint4*)(xr + (size_t)gw1 * 32 + gc1);
            if (t < 40 && (unsigned)gw2 < (unsigned)W1_) z2 = *(const uint4*)(xr + (size_t)gw2 * 32 + gc2);
        }

        const int r = rbase + rr;
        if (r >= 0 && r < H1_) {
            // per-hh A pointers (kh = rr - 2*hh), validity hoisted
            const uint4* ap[4];
            bool av[4];
#pragma unroll
            for (int hh = 0; hh < 4; ++hh) {
                int kh = rr - 2 * hh;
                av[hh] = ((unsigned)kh < 21u) && ((h0 + hh) < H2_);
                ap[hh] = (const uint4*)wf2 + (size_t)(av[hh] ? kh : 0) * (22 * 64) + lane;
            }
            const char* bb = sbuf + p * ROWB2 + bro;
#pragma unroll
            for (int ch = 0; ch < 2; ++ch) {
#pragma unroll
                for (int kw = 0; kw < 11; ++kw) {
                    uint4 bu = *(const uint4*)(bb + kw * 80 + ch * 32);
                    v8bf bv = __builtin_bit_cast(v8bf, bu);
#pragma unroll
                    for (int hh = 0; hh < 4; ++hh) {
                        if (av[hh]) {
                            uint4 au = ap[hh][(kw * 2 + ch) * 64];
                            acc[hh] = __builtin_amdgcn_mfma_f32_32x32x16_bf16(
                                __builtin_bit_cast(v8bf, au), bv, acc[hh], 0, 0, 0);
                        }
                    }
                }
            }
        }

        if (sv) {
            char* wb = sbuf + (p ^ 1) * ROWB2;
            *(uint4*)(wb + st0) = z0;
            *(uint4*)(wb + st1) = z1;
            if (t < 40) *(uint4*)(wb + st2) = z2;
        }
        __syncthreads();
    }

    // epilogue
    const int l2 = lens1[b];
    const int w  = w0 + wv * 32 + l31;
    const bool keep = (w < l2);
#pragma unroll
    for (int hh = 0; hh < 4; ++hh) {
        const int h = h0 + hh;
        if (h < H2_) {
#pragma unroll
            for (int reg = 0; reg < 16; ++reg) {
                int oc = (reg & 3) + 8 * (reg >> 2) + 4 * lhi;
                float v = fmaf(acc[hh][reg], scsh[64 + oc], scsh[96 + oc]);
                v = fminf(fmaxf(v, 0.f), 20.f);
                out[(((size_t)b * C2_ + oc) * H2_ + h) * W2_ + w] = keep ? v : 0.f;
            }
        }
    }
}

// ---------------------------------------------------------------------------
extern "C" void kernel_launch(void* const* d_in, const int* in_sizes, int n_in,
                              void* d_out, int out_size, void* d_ws, size_t ws_size,
                              hipStream_t stream) {
    const float* inputs = (const float*)d_in[0];
    const int*   slen   = (const int*)d_in[1];
    const float* w1 = (const float*)d_in[2];
    const float* b1 = (const float*)d_in[3];
    const float* g1 = (const float*)d_in[4];
    const float* be1 = (const float*)d_in[5];
    const float* m1 = (const float*)d_in[6];
    const float* v1 = (const float*)d_in[7];
    const float* w2 = (const float*)d_in[8];
    const float* b2 = (const float*)d_in[9];
    const float* g2 = (const float*)d_in[10];
    const float* be2 = (const float*)d_in[11];
    const float* m2 = (const float*)d_in[12];
    const float* v2 = (const float*)d_in[13];

    char* ws = (char*)d_ws;
    unsigned short* wf2  = (unsigned short*)(ws + WF2_B);
    unsigned short* wf1  = (unsigned short*)(ws + WF1_B);
    float*          scsh = (float*)(ws + SCSH_B);
    int*            lens1 = (int*)(ws + LENS1_B);
    unsigned short* xbf  = (unsigned short*)(ws + XBF_B);
    unsigned short* xg   = (unsigned short*)(ws + XG_B);

    float* out_x    = (float*)d_out;
    float* out_lens = out_x + OUT_X_SZ;

    hipLaunchKernelGGL(prep_kernel, dim3(1024), dim3(256), 0, stream,
                       inputs, w1, b1, g1, be1, m1, v1, w2, b2, g2, be2, m2, v2,
                       slen, wf1, wf2, xbf, scsh, lens1, out_lens);

    hipLaunchKernelGGL(conv1_mfma, dim3(4, 21, B_), dim3(256), 0, stream,
                       xbf, wf1, scsh, lens1, xg);

    hipLaunchKernelGGL(conv2_mfma, dim3(4, 11, B_), dim3(256), 0, stream,
                       xg, wf2, scsh, lens1, out_x);
}

// Round 5
// 726.650 us; speedup vs baseline: 1.0303x; 1.0303x over previous
//
#include <hip/hip_runtime.h>
#include <math.h>

// Problem constants
#define B_    32
#define H_IN  161
#define W_IN  1024
#define C1_   32
#define H1_   81
#define W1_   512
#define C2_   32
#define H2_   41
#define W2_   512

#define OUT_X_SZ ((size_t)B_ * C2_ * H2_ * W2_)            // 21,495,808

// ws byte offsets (all 16B-aligned)
#define WF2_B    0u            // 236544 bf16 (conv2 weights, A-frag order)
#define WF1_B    473088u       // 41*512 bf16 (conv1 weights, A-frag order, k 11->16 zero-pad)
#define SCSH_B   515072u       // 128 fp32
#define LENS1_B  515584u       // 32 int
#define XBF_B    515712u       // 32*161*1048 bf16 padded input = 10,798,592 B
#define XG_B     11314304u     // 32*81*512*32 bf16 = 84,934,656 B

#define WF2_N    236544
#define WF1_N    20992         // 41 * 512
#define XBF_ROW  1048          // slots per padded row; slot = col + 5
#define XBF_N    (32 * 161 * XBF_ROW)

typedef __bf16 v8bf __attribute__((ext_vector_type(8)));
typedef float v16f __attribute__((ext_vector_type(16)));

static __device__ __forceinline__ unsigned short f2bf(float f) {
    unsigned int u = __float_as_uint(f);
    unsigned int r = (u + 0x7fffu + ((u >> 16) & 1u)) >> 16;
    return (unsigned short)r;
}

// ---------------------------------------------------------------------------
// Prep (unchanged from R4): pack weights to MFMA A-frag order, fold BN,
// compute lens, convert input to zero-padded bf16 rows (slot = col+5).
// ---------------------------------------------------------------------------
__global__ void prep_kernel(const float* __restrict__ x,
                            const float* __restrict__ w1, const float* __restrict__ b1,
                            const float* __restrict__ g1, const float* __restrict__ be1,
                            const float* __restrict__ m1, const float* __restrict__ v1,
                            const float* __restrict__ w2, const float* __restrict__ b2,
                            const float* __restrict__ g2, const float* __restrict__ be2,
                            const float* __restrict__ m2, const float* __restrict__ v2,
                            const int* __restrict__ lens,
                            unsigned short* __restrict__ wf1, unsigned short* __restrict__ wf2,
                            unsigned short* __restrict__ xbf,
                            float* __restrict__ scsh, int* __restrict__ lens1,
                            float* __restrict__ out_lens)
{
    const int i = blockIdx.x * blockDim.x + threadIdx.x;
    const int stride = gridDim.x * blockDim.x;

    for (int idx = i; idx < XBF_N; idx += stride) {
        int s  = idx % XBF_ROW;
        int br = idx / XBF_ROW;
        int c  = s - 5;
        float v = 0.f;
        if ((unsigned)c < (unsigned)W_IN) v = x[(size_t)br * W_IN + c];
        xbf[idx] = f2bf(v);
    }
    for (int idx = i; idx < WF2_N; idx += stride) {
        int j  = idx & 7;
        int l  = (idx >> 3) & 63;
        int f  = idx >> 9;
        int ch = f & 1;
        int kwkh = f >> 1;
        int kw = kwkh % 11;
        int kh = kwkh / 11;
        int oc = l & 31;
        int c  = ch * 16 + ((l >> 5) << 3) + j;
        wf2[idx] = f2bf(w2[((oc * 32 + c) * 21 + kh) * 11 + kw]);
    }
    for (int idx = i; idx < WF1_N; idx += stride) {
        int j  = idx & 7;
        int l  = (idx >> 3) & 63;
        int kh = idx >> 9;
        int k  = ((l >> 5) << 3) + j;
        int oc = l & 31;
        wf1[idx] = (k < 11) ? f2bf(w1[oc * 451 + kh * 11 + k]) : (unsigned short)0;
    }
    if (i < 32) {
        float s1 = g1[i] / sqrtf(v1[i] + 1e-5f);
        scsh[i]      = s1;
        scsh[32 + i] = b1[i] * s1 + be1[i] - m1[i] * s1;
        float s2 = g2[i] / sqrtf(v2[i] + 1e-5f);
        scsh[64 + i] = s2;
        scsh[96 + i] = b2[i] * s2 + be2[i] - m2[i] * s2;
        int l1 = (lens[i] - 1) / 2 + 1;
        if (l1 > W1_) l1 = W1_;
        lens1[i] = l1;
        out_lens[i] = (float)l1;
    }
}

// ---------------------------------------------------------------------------
// Conv1 MFMA: A (all 41 KB of wf1) staged in LDS once per block; B direct
// from global (L1-hot padded bf16 rows). Wave tile = 64w (Nt=2) x 4h (Hb=4).
// Wave-level mask-skip (no barriers in main loop).
// ---------------------------------------------------------------------------
__global__ __launch_bounds__(256, 2) void conv1_mfma(
    const unsigned short* __restrict__ xbf,  // [32][161][1048] padded bf16
    const unsigned short* __restrict__ wf1,
    const float* __restrict__ scsh,
    const int* __restrict__ lens1,
    unsigned short* __restrict__ xg)         // [32][81][512][32] bf16
{
    const int t    = threadIdx.x;
    const int lane = t & 63;
    const int l31  = lane & 31;
    const int lhi  = lane >> 5;
    const int wv   = t >> 6;
    const int Wl   = blockIdx.x * 256 + wv * 64;   // wave w-base, 2 n-tiles of 32
    const int h0   = blockIdx.y * 4;
    const int b    = blockIdx.z;

    __shared__ __align__(16) uint4 swf[41 * 64];   // 41,984 B: wf1 fragments

    // cooperative copy of wf1 into LDS
#pragma unroll
    for (int k = 0; k < 11; ++k) {
        int idx = t + k * 256;
        if (idx < 41 * 64) swf[idx] = ((const uint4*)wf1)[idx];
    }
    __syncthreads();

    const int l1 = lens1[b];

    v16f acc[2][4];
#pragma unroll
    for (int nt = 0; nt < 2; ++nt)
#pragma unroll
        for (int hh = 0; hh < 4; ++hh)
#pragma unroll
            for (int i = 0; i < 16; ++i) acc[nt][hh][i] = 0.f;

    if (Wl < l1) {   // wave-level mask skip (no barriers below)
        const char* xrow0 = (const char*)(xbf + (size_t)b * (H_IN * XBF_ROW));
        const int boff = 4 * (Wl + l31) + 16 * lhi;     // bytes; +128 for nt=1

        for (int rr = 0; rr < 47; ++rr) {
            const int r = 2 * h0 - 20 + rr;
            if (r < 0 || r >= H_IN) continue;

            const char* rowb = xrow0 + (size_t)r * (XBF_ROW * 2);
            uint4 bu0 = *(const uint4*)(rowb + boff);
            uint4 bu1 = *(const uint4*)(rowb + boff + 128);
            v8bf bv0 = __builtin_bit_cast(v8bf, bu0);
            v8bf bv1 = __builtin_bit_cast(v8bf, bu1);

#pragma unroll
            for (int hh = 0; hh < 4; ++hh) {
                const int kh = rr - 2 * hh;
                if ((unsigned)kh < 41u && (h0 + hh) < H1_) {
                    uint4 au = swf[kh * 64 + lane];
                    v8bf a = __builtin_bit_cast(v8bf, au);
                    acc[0][hh] = __builtin_amdgcn_mfma_f32_32x32x16_bf16(a, bv0, acc[0][hh], 0, 0, 0);
                    acc[1][hh] = __builtin_amdgcn_mfma_f32_32x32x16_bf16(a, bv1, acc[1][hh], 0, 0, 0);
                }
            }
        }
    }

    // epilogue: BN + hardtanh + mask, write xg[b][h][w][c] bf16
#pragma unroll
    for (int nt = 0; nt < 2; ++nt) {
        const int w = Wl + nt * 32 + l31;
        const bool keep = (w < l1);
#pragma unroll
        for (int hh = 0; hh < 4; ++hh) {
            const int h = h0 + hh;
            if (h < H1_) {
                unsigned short* dp = xg + (((size_t)b * H1_ + h) * W1_ + w) * 32;
#pragma unroll
                for (int rq = 0; rq < 4; ++rq) {
                    unsigned int wd[2];
#pragma unroll
                    for (int d = 0; d < 2; ++d) {
                        int rg = rq * 4 + d * 2;
                        int oc = 8 * rq + 4 * lhi + d * 2;
                        float v0 = fminf(fmaxf(fmaf(acc[nt][hh][rg],     scsh[oc],     scsh[32 + oc]), 0.f), 20.f);
                        float v1 = fminf(fmaxf(fmaf(acc[nt][hh][rg + 1], scsh[oc + 1], scsh[33 + oc]), 0.f), 20.f);
                        if (!keep) { v0 = 0.f; v1 = 0.f; }
                        wd[d] = (unsigned int)f2bf(v0) | ((unsigned int)f2bf(v1) << 16);
                    }
                    uint2 u; u.x = wd[0]; u.y = wd[1];
                    *(uint2*)(dp + 8 * rq + 4 * lhi) = u;
                }
            }
        }
    }
}

// ---------------------------------------------------------------------------
// Conv2 MFMA: Nt=4 (A-L1 = 0.25 KB/MFMA) x Hb=4 (B-LDS = 0.25 KB/MFMA).
// Block = 128 threads (2 waves), tile 256w x 4h; wave tile 128w x 4h,
// acc = 4x4x16 = 256 VGPR. Block-uniform mask-skip (barrier-safe).
// LDS: input row 266 slots x 80 B, double-buffered (42,560 B).
// ---------------------------------------------------------------------------
#define ROWB2 21280   // 266 * 80

__global__ __launch_bounds__(128, 1) void conv2_mfma(
    const unsigned short* __restrict__ xg,   // [32][81][512][32] bf16
    const unsigned short* __restrict__ wf2,  // frag-ordered
    const float* __restrict__ scsh,
    const int* __restrict__ lens1,
    float* __restrict__ out)                 // [32][32][41][512] fp32
{
    const int t    = threadIdx.x;
    const int lane = t & 63;
    const int l31  = lane & 31;
    const int lhi  = lane >> 5;
    const int wv   = t >> 6;                 // 0..1
    const int w0   = blockIdx.x * 256;
    const int h0   = blockIdx.y * 4;
    const int b    = blockIdx.z;

    __shared__ __align__(16) char sbuf[2 * ROWB2];

    const int l1 = lens1[b];
    const bool active = (w0 < l1);           // block-uniform

    v16f acc[4][4];                          // [nt][hh]
#pragma unroll
    for (int nt = 0; nt < 4; ++nt)
#pragma unroll
        for (int hh = 0; hh < 4; ++hh)
#pragma unroll
            for (int i = 0; i < 16; ++i) acc[nt][hh][i] = 0.f;

    if (active) {
        // staging geometry: element k handles uint4 #(t + 128k), k=0..8
        const int s0    = t >> 2;            // slot
        const int ckk   = t & 3;             // 16B chunk within slot
        const int gbase = w0 - 5 + s0;       // +32 per k
        const int lbase = s0 * 80 + ckk * 16;
        const int goff  = ckk * 8;           // element offset in c

        const unsigned short* xb = xg + (size_t)b * (H1_ * W1_ * 32);
        const int rbase = 2 * h0 - 10;

        // prologue: stage row rbase into buffer 0
        if (rbase >= 0 && rbase < H1_) {
            const unsigned short* xr = xb + (size_t)rbase * (W1_ * 32);
#pragma unroll
            for (int k = 0; k < 9; ++k) {
                if (k < 8 || t < 40) {
                    int gw = gbase + 32 * k;
                    uint4 z = {0, 0, 0, 0};
                    if ((unsigned)gw < (unsigned)W1_) z = *(const uint4*)(xr + (size_t)gw * 32 + goff);
                    *(uint4*)(sbuf + lbase + k * 2560) = z;
                }
            }
        }
        __syncthreads();

        const int bro = (wv * 128 + l31) * 80 + lhi * 16;  // + nt*2560 + kw*80 + ch*32

        for (int rr = 0; rr < 27; ++rr) {
            const int p  = rr & 1;
            const int rn = rbase + rr + 1;
            const bool sv = (rr < 26) && rn >= 0 && rn < H1_;

            uint4 z[9];
#pragma unroll
            for (int k = 0; k < 9; ++k) { z[k].x = 0; z[k].y = 0; z[k].z = 0; z[k].w = 0; }
            if (sv) {
                const unsigned short* xr = xb + (size_t)rn * (W1_ * 32);
#pragma unroll
                for (int k = 0; k < 9; ++k) {
                    if (k < 8 || t < 40) {
                        int gw = gbase + 32 * k;
                        if ((unsigned)gw < (unsigned)W1_) z[k] = *(const uint4*)(xr + (size_t)gw * 32 + goff);
                    }
                }
            }

            const int r = rbase + rr;
            if (r >= 0 && r < H1_) {
                int  khs[4];
                bool av[4];
#pragma unroll
                for (int hh = 0; hh < 4; ++hh) {
                    khs[hh] = rr - 2 * hh;
                    av[hh]  = ((unsigned)khs[hh] < 21u) && ((h0 + hh) < H2_);
                }
                const char* bb = sbuf + p * ROWB2 + bro;
                const char* wb = (const char*)wf2;
#pragma unroll
                for (int kw = 0; kw < 11; ++kw) {
#pragma unroll
                    for (int ch = 0; ch < 2; ++ch) {
                        uint4 a[4];
#pragma unroll
                        for (int hh = 0; hh < 4; ++hh)
                            if (av[hh])
                                a[hh] = *(const uint4*)(wb + (size_t)((khs[hh] * 11 + kw) * 2 + ch) * 1024 + lane * 16);
#pragma unroll
                        for (int nt = 0; nt < 4; ++nt) {
                            uint4 bu = *(const uint4*)(bb + nt * 2560 + kw * 80 + ch * 32);
                            v8bf bv = __builtin_bit_cast(v8bf, bu);
#pragma unroll
                            for (int hh = 0; hh < 4; ++hh)
                                if (av[hh])
                                    acc[nt][hh] = __builtin_amdgcn_mfma_f32_32x32x16_bf16(
                                        __builtin_bit_cast(v8bf, a[hh]), bv, acc[nt][hh], 0, 0, 0);
                        }
                    }
                }
            }

            if (sv) {
                char* wbuf = sbuf + (p ^ 1) * ROWB2;
#pragma unroll
                for (int k = 0; k < 9; ++k)
                    if (k < 8 || t < 40) *(uint4*)(wbuf + lbase + k * 2560) = z[k];
            }
            __syncthreads();
        }
    }

    // epilogue (runs for all blocks; inactive blocks write zeros via keep-mask)
#pragma unroll
    for (int nt = 0; nt < 4; ++nt) {
        const int w = w0 + wv * 128 + nt * 32 + l31;
        const bool keep = (w < l1);
#pragma unroll
        for (int hh = 0; hh < 4; ++hh) {
            const int h = h0 + hh;
            if (h < H2_) {
#pragma unroll
                for (int reg = 0; reg < 16; ++reg) {
                    int oc = (reg & 3) + 8 * (reg >> 2) + 4 * lhi;
                    float v = fmaf(acc[nt][hh][reg], scsh[64 + oc], scsh[96 + oc]);
                    v = fminf(fmaxf(v, 0.f), 20.f);
                    out[(((size_t)b * C2_ + oc) * H2_ + h) * W2_ + w] = keep ? v : 0.f;
                }
            }
        }
    }
}

// ---------------------------------------------------------------------------
extern "C" void kernel_launch(void* const* d_in, const int* in_sizes, int n_in,
                              void* d_out, int out_size, void* d_ws, size_t ws_size,
                              hipStream_t stream) {
    const float* inputs = (const float*)d_in[0];
    const int*   slen   = (const int*)d_in[1];
    const float* w1 = (const float*)d_in[2];
    const float* b1 = (const float*)d_in[3];
    const float* g1 = (const float*)d_in[4];
    const float* be1 = (const float*)d_in[5];
    const float* m1 = (const float*)d_in[6];
    const float* v1 = (const float*)d_in[7];
    const float* w2 = (const float*)d_in[8];
    const float* b2 = (const float*)d_in[9];
    const float* g2 = (const float*)d_in[10];
    const float* be2 = (const float*)d_in[11];
    const float* m2 = (const float*)d_in[12];
    const float* v2 = (const float*)d_in[13];

    char* ws = (char*)d_ws;
    unsigned short* wf2  = (unsigned short*)(ws + WF2_B);
    unsigned short* wf1  = (unsigned short*)(ws + WF1_B);
    float*          scsh = (float*)(ws + SCSH_B);
    int*            lens1 = (int*)(ws + LENS1_B);
    unsigned short* xbf  = (unsigned short*)(ws + XBF_B);
    unsigned short* xg   = (unsigned short*)(ws + XG_B);

    float* out_x    = (float*)d_out;
    float* out_lens = out_x + OUT_X_SZ;

    hipLaunchKernelGGL(prep_kernel, dim3(1024), dim3(256), 0, stream,
                       inputs, w1, b1, g1, be1, m1, v1, w2, b2, g2, be2, m2, v2,
                       slen, wf1, wf2, xbf, scsh, lens1, out_lens);

    hipLaunchKernelGGL(conv1_mfma, dim3(2, 21, B_), dim3(256), 0, stream,
                       xbf, wf1, scsh, lens1, xg);

    hipLaunchKernelGGL(conv2_mfma, dim3(2, 11, B_), dim3(128), 0, stream,
                       xg, wf2, scsh, lens1, out_x);
}

// Round 6
// 592.220 us; speedup vs baseline: 1.2642x; 1.2270x over previous
//
#include <hip/hip_runtime.h>
#include <math.h>

// Problem constants
#define B_    32
#define H_IN  161
#define W_IN  1024
#define C1_   32
#define H1_   81
#define W1_   512
#define C2_   32
#define H2_   41
#define W2_   512

#define OUT_X_SZ ((size_t)B_ * C2_ * H2_ * W2_)            // 21,495,808

// ws byte offsets (all 16B-aligned)
#define WF2_B    0u            // 236544 bf16 (conv2 weights, A-frag order)
#define WF1_B    473088u       // 41*512 bf16 (conv1 weights, A-frag order, k 11->16 zero-pad)
#define SCSH_B   515072u       // 128 fp32
#define LENS1_B  515584u       // 32 int
#define XBF_B    515712u       // 32*161*1048 bf16 padded input = 10,798,592 B
#define XG_B     11314304u     // 32*81*512*32 bf16 = 84,934,656 B

#define WF2_N    236544
#define WF1_N    20992         // 41 * 512
#define XBF_ROW  1048          // slots per padded row; slot = col + 5
#define XBF_N    (32 * 161 * XBF_ROW)

typedef __bf16 v8bf __attribute__((ext_vector_type(8)));
typedef float v16f __attribute__((ext_vector_type(16)));

static __device__ __forceinline__ unsigned short f2bf(float f) {
    unsigned int u = __float_as_uint(f);
    unsigned int r = (u + 0x7fffu + ((u >> 16) & 1u)) >> 16;
    return (unsigned short)r;
}

// ---------------------------------------------------------------------------
// Prep (unchanged): pack weights to MFMA A-frag order, fold BN, compute lens,
// convert input to zero-padded bf16 rows (slot = col+5).
// ---------------------------------------------------------------------------
__global__ void prep_kernel(const float* __restrict__ x,
                            const float* __restrict__ w1, const float* __restrict__ b1,
                            const float* __restrict__ g1, const float* __restrict__ be1,
                            const float* __restrict__ m1, const float* __restrict__ v1,
                            const float* __restrict__ w2, const float* __restrict__ b2,
                            const float* __restrict__ g2, const float* __restrict__ be2,
                            const float* __restrict__ m2, const float* __restrict__ v2,
                            const int* __restrict__ lens,
                            unsigned short* __restrict__ wf1, unsigned short* __restrict__ wf2,
                            unsigned short* __restrict__ xbf,
                            float* __restrict__ scsh, int* __restrict__ lens1,
                            float* __restrict__ out_lens)
{
    const int i = blockIdx.x * blockDim.x + threadIdx.x;
    const int stride = gridDim.x * blockDim.x;

    for (int idx = i; idx < XBF_N; idx += stride) {
        int s  = idx % XBF_ROW;
        int br = idx / XBF_ROW;
        int c  = s - 5;
        float v = 0.f;
        if ((unsigned)c < (unsigned)W_IN) v = x[(size_t)br * W_IN + c];
        xbf[idx] = f2bf(v);
    }
    for (int idx = i; idx < WF2_N; idx += stride) {
        int j  = idx & 7;
        int l  = (idx >> 3) & 63;
        int f  = idx >> 9;
        int ch = f & 1;
        int kwkh = f >> 1;
        int kw = kwkh % 11;
        int kh = kwkh / 11;
        int oc = l & 31;
        int c  = ch * 16 + ((l >> 5) << 3) + j;
        wf2[idx] = f2bf(w2[((oc * 32 + c) * 21 + kh) * 11 + kw]);
    }
    for (int idx = i; idx < WF1_N; idx += stride) {
        int j  = idx & 7;
        int l  = (idx >> 3) & 63;
        int kh = idx >> 9;
        int k  = ((l >> 5) << 3) + j;
        int oc = l & 31;
        wf1[idx] = (k < 11) ? f2bf(w1[oc * 451 + kh * 11 + k]) : (unsigned short)0;
    }
    if (i < 32) {
        float s1 = g1[i] / sqrtf(v1[i] + 1e-5f);
        scsh[i]      = s1;
        scsh[32 + i] = b1[i] * s1 + be1[i] - m1[i] * s1;
        float s2 = g2[i] / sqrtf(v2[i] + 1e-5f);
        scsh[64 + i] = s2;
        scsh[96 + i] = b2[i] * s2 + be2[i] - m2[i] * s2;
        int l1 = (lens[i] - 1) / 2 + 1;
        if (l1 > W1_) l1 = W1_;
        lens1[i] = l1;
        out_lens[i] = (float)l1;
    }
}

// ---------------------------------------------------------------------------
// Conv1 MFMA: A (41 KB wf1) in LDS; B from global (L1/L2-hot padded rows).
// Block 256 = 4 waves, arranged 2w x 2h. Wave tile: Nt=2 (64w) x Hb=2 (2h).
// acc = 4 v16f = 64 VGPR. Wave-level mask skip; no barriers in main loop.
// ---------------------------------------------------------------------------
__global__ __launch_bounds__(256, 3) void conv1_mfma(
    const unsigned short* __restrict__ xbf,  // [32][161][1048] padded bf16
    const unsigned short* __restrict__ wf1,
    const float* __restrict__ scsh,
    const int* __restrict__ lens1,
    unsigned short* __restrict__ xg)         // [32][81][512][32] bf16
{
    const int t     = threadIdx.x;
    const int lane  = t & 63;
    const int l31   = lane & 31;
    const int lhi   = lane >> 5;
    const int wv    = t >> 6;
    const int wsub  = (wv & 1) * 64;
    const int hpair = wv >> 1;
    const int Wl    = blockIdx.x * 128 + wsub;     // wave w-base (2 n-tiles of 32)
    const int h0b   = blockIdx.y * 4;              // block h-base
    const int b     = blockIdx.z;

    __shared__ __align__(16) uint4 swf[41 * 64];   // 41,984 B

#pragma unroll
    for (int k = 0; k < 11; ++k) {
        int idx = t + k * 256;
        if (idx < 41 * 64) swf[idx] = ((const uint4*)wf1)[idx];
    }
    __syncthreads();

    const int l1 = lens1[b];

    v16f acc[2][2];                                // [nt][hl]
#pragma unroll
    for (int nt = 0; nt < 2; ++nt)
#pragma unroll
        for (int hl = 0; hl < 2; ++hl)
#pragma unroll
            for (int i = 0; i < 16; ++i) acc[nt][hl][i] = 0.f;

    if (Wl < l1) {                                 // wave-uniform mask skip
        const char* xrow0 = (const char*)(xbf + (size_t)b * (H_IN * XBF_ROW));
        const int boff = 4 * (Wl + l31) + 16 * lhi;

        for (int rr = 0; rr < 47; ++rr) {
            const int r = 2 * h0b - 20 + rr;
            if (r < 0 || r >= H_IN) continue;

            const int kh0 = rr - 4 * hpair;        // hl=0
            const int kh1 = kh0 - 2;               // hl=1
            const int hg0 = h0b + 2 * hpair;
            const bool av0 = ((unsigned)kh0 < 41u) && (hg0 < H1_);
            const bool av1 = ((unsigned)kh1 < 41u) && (hg0 + 1 < H1_);
            if (!av0 && !av1) continue;

            const char* rowb = xrow0 + (size_t)r * (XBF_ROW * 2);
            uint4 bu0 = *(const uint4*)(rowb + boff);
            uint4 bu1 = *(const uint4*)(rowb + boff + 128);
            v8bf bv0 = __builtin_bit_cast(v8bf, bu0);
            v8bf bv1 = __builtin_bit_cast(v8bf, bu1);

            if (av0) {
                v8bf a = __builtin_bit_cast(v8bf, swf[kh0 * 64 + lane]);
                acc[0][0] = __builtin_amdgcn_mfma_f32_32x32x16_bf16(a, bv0, acc[0][0], 0, 0, 0);
                acc[1][0] = __builtin_amdgcn_mfma_f32_32x32x16_bf16(a, bv1, acc[1][0], 0, 0, 0);
            }
            if (av1) {
                v8bf a = __builtin_bit_cast(v8bf, swf[kh1 * 64 + lane]);
                acc[0][1] = __builtin_amdgcn_mfma_f32_32x32x16_bf16(a, bv0, acc[0][1], 0, 0, 0);
                acc[1][1] = __builtin_amdgcn_mfma_f32_32x32x16_bf16(a, bv1, acc[1][1], 0, 0, 0);
            }
        }
    }

    // epilogue: BN + hardtanh + mask, write xg[b][h][w][c] bf16
#pragma unroll
    for (int nt = 0; nt < 2; ++nt) {
        const int w = Wl + nt * 32 + l31;
        const bool keep = (w < l1);
#pragma unroll
        for (int hl = 0; hl < 2; ++hl) {
            const int h = h0b + 2 * hpair + hl;
            if (h < H1_) {
                unsigned short* dp = xg + (((size_t)b * H1_ + h) * W1_ + w) * 32;
#pragma unroll
                for (int rq = 0; rq < 4; ++rq) {
                    unsigned int wd[2];
#pragma unroll
                    for (int d = 0; d < 2; ++d) {
                        int rg = rq * 4 + d * 2;
                        int oc = 8 * rq + 4 * lhi + d * 2;
                        float v0 = fminf(fmaxf(fmaf(acc[nt][hl][rg],     scsh[oc],     scsh[32 + oc]), 0.f), 20.f);
                        float v1 = fminf(fmaxf(fmaf(acc[nt][hl][rg + 1], scsh[oc + 1], scsh[33 + oc]), 0.f), 20.f);
                        if (!keep) { v0 = 0.f; v1 = 0.f; }
                        wd[d] = (unsigned int)f2bf(v0) | ((unsigned int)f2bf(v1) << 16);
                    }
                    uint2 u; u.x = wd[0]; u.y = wd[1];
                    *(uint2*)(dp + 8 * rq + 4 * lhi) = u;
                }
            }
        }
    }
}

// ---------------------------------------------------------------------------
// Conv2 MFMA: block 256 = 4 waves (2w x 2h), block tile 128w x 4h.
// Wave tile: Nt=2 (64w) x Hb=2. acc = 4 v16f = 64 VGPR.
// Per MFMA: A = 0.5 KB (global, pairwise L1 reuse), B = 0.5 ds_read_b128.
// LDS: row of 138 slots x 80B, double-buffered = 22,080 B. ~3 blocks/CU.
// ---------------------------------------------------------------------------
#define ROWB2 11040   // 138 * 80

__global__ __launch_bounds__(256, 3) void conv2_mfma(
    const unsigned short* __restrict__ xg,   // [32][81][512][32] bf16
    const unsigned short* __restrict__ wf2,  // frag-ordered
    const float* __restrict__ scsh,
    const int* __restrict__ lens1,
    float* __restrict__ out)                 // [32][32][41][512] fp32
{
    const int t     = threadIdx.x;
    const int lane  = t & 63;
    const int l31   = lane & 31;
    const int lhi   = lane >> 5;
    const int wv    = t >> 6;
    const int wsub  = (wv & 1) * 64;
    const int hpair = wv >> 1;
    const int w0    = blockIdx.x * 128;
    const int h0    = blockIdx.y * 4;
    const int b     = blockIdx.z;

    __shared__ __align__(16) char sbuf[2 * ROWB2];

    const int l1 = lens1[b];
    const bool active = (w0 < l1);           // block-uniform

    v16f acc[2][2];                          // [nt][hl]
#pragma unroll
    for (int nt = 0; nt < 2; ++nt)
#pragma unroll
        for (int hl = 0; hl < 2; ++hl)
#pragma unroll
            for (int i = 0; i < 16; ++i) acc[nt][hl][i] = 0.f;

    if (active) {
        // staging: 552 uint4 chunks (138 slots x 4); thread t covers i=t, t+256, t+512(<552)
        const int s0    = t >> 2;
        const int ck    = t & 3;
        const int gbase = w0 - 5 + s0;       // +64 per staging step of 256 chunks
        const int lbase = s0 * 80 + ck * 16;
        const int goff  = ck * 8;

        const unsigned short* xb = xg + (size_t)b * (H1_ * W1_ * 32);
        const int rbase = 2 * h0 - 10;

        if (rbase >= 0 && rbase < H1_) {
            const unsigned short* xr = xb + (size_t)rbase * (W1_ * 32);
#pragma unroll
            for (int k = 0; k < 3; ++k) {
                if (k < 2 || t < 40) {
                    int gw = gbase + 64 * k;
                    uint4 z = {0, 0, 0, 0};
                    if ((unsigned)gw < (unsigned)W1_) z = *(const uint4*)(xr + (size_t)gw * 32 + goff);
                    *(uint4*)(sbuf + lbase + k * 5120) = z;
                }
            }
        }
        __syncthreads();

        const int bro = (wsub + l31) * 80 + lhi * 16;   // + nt*2560 + kw*80 + ch*32

        for (int rr = 0; rr < 27; ++rr) {
            const int p  = rr & 1;
            const int rn = rbase + rr + 1;
            const bool sv = (rr < 26) && rn >= 0 && rn < H1_;

            uint4 z[3];
#pragma unroll
            for (int k = 0; k < 3; ++k) { z[k].x = 0; z[k].y = 0; z[k].z = 0; z[k].w = 0; }
            if (sv) {
                const unsigned short* xr = xb + (size_t)rn * (W1_ * 32);
#pragma unroll
                for (int k = 0; k < 3; ++k) {
                    if (k < 2 || t < 40) {
                        int gw = gbase + 64 * k;
                        if ((unsigned)gw < (unsigned)W1_) z[k] = *(const uint4*)(xr + (size_t)gw * 32 + goff);
                    }
                }
            }

            const int r = rbase + rr;
            if (r >= 0 && r < H1_) {
                const int kh0 = rr - 4 * hpair;
                const int kh1 = kh0 - 2;
                const int hg0 = h0 + 2 * hpair;
                const bool av0 = ((unsigned)kh0 < 21u) && (hg0 < H2_);
                const bool av1 = ((unsigned)kh1 < 21u) && (hg0 + 1 < H2_);
                const char* bb = sbuf + p * ROWB2 + bro;
                const char* wb = (const char*)wf2;
#pragma unroll
                for (int kw = 0; kw < 11; ++kw) {
#pragma unroll
                    for (int ch = 0; ch < 2; ++ch) {
                        uint4 b0u = *(const uint4*)(bb + kw * 80 + ch * 32);
                        uint4 b1u = *(const uint4*)(bb + 2560 + kw * 80 + ch * 32);
                        v8bf bv0 = __builtin_bit_cast(v8bf, b0u);
                        v8bf bv1 = __builtin_bit_cast(v8bf, b1u);
                        if (av0) {
                            uint4 au = *(const uint4*)(wb + (size_t)((kh0 * 11 + kw) * 2 + ch) * 1024 + lane * 16);
                            v8bf a = __builtin_bit_cast(v8bf, au);
                            acc[0][0] = __builtin_amdgcn_mfma_f32_32x32x16_bf16(a, bv0, acc[0][0], 0, 0, 0);
                            acc[1][0] = __builtin_amdgcn_mfma_f32_32x32x16_bf16(a, bv1, acc[1][0], 0, 0, 0);
                        }
                        if (av1) {
                            uint4 au = *(const uint4*)(wb + (size_t)((kh1 * 11 + kw) * 2 + ch) * 1024 + lane * 16);
                            v8bf a = __builtin_bit_cast(v8bf, au);
                            acc[0][1] = __builtin_amdgcn_mfma_f32_32x32x16_bf16(a, bv0, acc[0][1], 0, 0, 0);
                            acc[1][1] = __builtin_amdgcn_mfma_f32_32x32x16_bf16(a, bv1, acc[1][1], 0, 0, 0);
                        }
                    }
                }
            }

            if (sv) {
                char* wbuf = sbuf + (p ^ 1) * ROWB2;
#pragma unroll
                for (int k = 0; k < 3; ++k)
                    if (k < 2 || t < 40) *(uint4*)(wbuf + lbase + k * 5120) = z[k];
            }
            __syncthreads();
        }
    }

    // epilogue (all blocks; inactive ones write zeros via keep-mask)
#pragma unroll
    for (int nt = 0; nt < 2; ++nt) {
        const int w = w0 + wsub + nt * 32 + l31;
        const bool keep = (w < l1);
#pragma unroll
        for (int hl = 0; hl < 2; ++hl) {
            const int h = h0 + 2 * hpair + hl;
            if (h < H2_) {
#pragma unroll
                for (int reg = 0; reg < 16; ++reg) {
                    int oc = (reg & 3) + 8 * (reg >> 2) + 4 * lhi;
                    float v = fmaf(acc[nt][hl][reg], scsh[64 + oc], scsh[96 + oc]);
                    v = fminf(fmaxf(v, 0.f), 20.f);
                    out[(((size_t)b * C2_ + oc) * H2_ + h) * W2_ + w] = keep ? v : 0.f;
                }
            }
        }
    }
}

// ---------------------------------------------------------------------------
extern "C" void kernel_launch(void* const* d_in, const int* in_sizes, int n_in,
                              void* d_out, int out_size, void* d_ws, size_t ws_size,
                              hipStream_t stream) {
    const float* inputs = (const float*)d_in[0];
    const int*   slen   = (const int*)d_in[1];
    const float* w1 = (const float*)d_in[2];
    const float* b1 = (const float*)d_in[3];
    const float* g1 = (const float*)d_in[4];
    const float* be1 = (const float*)d_in[5];
    const float* m1 = (const float*)d_in[6];
    const float* v1 = (const float*)d_in[7];
    const float* w2 = (const float*)d_in[8];
    const float* b2 = (const float*)d_in[9];
    const float* g2 = (const float*)d_in[10];
    const float* be2 = (const float*)d_in[11];
    const float* m2 = (const float*)d_in[12];
    const float* v2 = (const float*)d_in[13];

    char* ws = (char*)d_ws;
    unsigned short* wf2  = (unsigned short*)(ws + WF2_B);
    unsigned short* wf1  = (unsigned short*)(ws + WF1_B);
    float*          scsh = (float*)(ws + SCSH_B);
    int*            lens1 = (int*)(ws + LENS1_B);
    unsigned short* xbf  = (unsigned short*)(ws + XBF_B);
    unsigned short* xg   = (unsigned short*)(ws + XG_B);

    float* out_x    = (float*)d_out;
    float* out_lens = out_x + OUT_X_SZ;

    hipLaunchKernelGGL(prep_kernel, dim3(1024), dim3(256), 0, stream,
                       inputs, w1, b1, g1, be1, m1, v1, w2, b2, g2, be2, m2, v2,
                       slen, wf1, wf2, xbf, scsh, lens1, out_lens);

    hipLaunchKernelGGL(conv1_mfma, dim3(4, 21, B_), dim3(256), 0, stream,
                       xbf, wf1, scsh, lens1, xg);

    hipLaunchKernelGGL(conv2_mfma, dim3(4, 11, B_), dim3(256), 0, stream,
                       xg, wf2, scsh, lens1, out_x);
}

// Round 7
// 576.071 us; speedup vs baseline: 1.2997x; 1.0280x over previous
//
#include <hip/hip_runtime.h>
#include <math.h>

// Problem constants
#define B_    32
#define H_IN  161
#define W_IN  1024
#define C1_   32
#define H1_   81
#define W1_   512
#define C2_   32
#define H2_   41
#define W2_   512

#define OUT_X_SZ ((size_t)B_ * C2_ * H2_ * W2_)            // 21,495,808

// ws byte offsets (all 16B-aligned)
#define WF2_B    0u            // 236544 bf16 (conv2 weights, A-frag order)
#define WF1_B    473088u       // 41*512 bf16 (conv1 weights, A-frag order, k 11->16 zero-pad)
#define SCSH_B   515072u       // 128 fp32
#define LENS1_B  515584u       // 32 int
#define XBF_B    515712u       // 32*161*1048 bf16 padded input = 10,798,592 B
#define XG_B     11314304u     // 32*81*512*32 bf16 = 84,934,656 B

#define WF2_N    236544
#define WF1_N    20992         // 41 * 512
#define XBF_ROW  1048          // slots per padded row; slot = col + 5
#define XBF_N    (32 * 161 * XBF_ROW)

typedef __bf16 v8bf __attribute__((ext_vector_type(8)));
typedef float v16f __attribute__((ext_vector_type(16)));

static __device__ __forceinline__ unsigned short f2bf(float f) {
    unsigned int u = __float_as_uint(f);
    unsigned int r = (u + 0x7fffu + ((u >> 16) & 1u)) >> 16;
    return (unsigned short)r;
}

// ---------------------------------------------------------------------------
// Prep (unchanged): pack weights to MFMA A-frag order, fold BN, compute lens,
// convert input to zero-padded bf16 rows (slot = col+5).
// ---------------------------------------------------------------------------
__global__ void prep_kernel(const float* __restrict__ x,
                            const float* __restrict__ w1, const float* __restrict__ b1,
                            const float* __restrict__ g1, const float* __restrict__ be1,
                            const float* __restrict__ m1, const float* __restrict__ v1,
                            const float* __restrict__ w2, const float* __restrict__ b2,
                            const float* __restrict__ g2, const float* __restrict__ be2,
                            const float* __restrict__ m2, const float* __restrict__ v2,
                            const int* __restrict__ lens,
                            unsigned short* __restrict__ wf1, unsigned short* __restrict__ wf2,
                            unsigned short* __restrict__ xbf,
                            float* __restrict__ scsh, int* __restrict__ lens1,
                            float* __restrict__ out_lens)
{
    const int i = blockIdx.x * blockDim.x + threadIdx.x;
    const int stride = gridDim.x * blockDim.x;

    for (int idx = i; idx < XBF_N; idx += stride) {
        int s  = idx % XBF_ROW;
        int br = idx / XBF_ROW;
        int c  = s - 5;
        float v = 0.f;
        if ((unsigned)c < (unsigned)W_IN) v = x[(size_t)br * W_IN + c];
        xbf[idx] = f2bf(v);
    }
    for (int idx = i; idx < WF2_N; idx += stride) {
        int j  = idx & 7;
        int l  = (idx >> 3) & 63;
        int f  = idx >> 9;
        int ch = f & 1;
        int kwkh = f >> 1;
        int kw = kwkh % 11;
        int kh = kwkh / 11;
        int oc = l & 31;
        int c  = ch * 16 + ((l >> 5) << 3) + j;
        wf2[idx] = f2bf(w2[((oc * 32 + c) * 21 + kh) * 11 + kw]);
    }
    for (int idx = i; idx < WF1_N; idx += stride) {
        int j  = idx & 7;
        int l  = (idx >> 3) & 63;
        int kh = idx >> 9;
        int k  = ((l >> 5) << 3) + j;
        int oc = l & 31;
        wf1[idx] = (k < 11) ? f2bf(w1[oc * 451 + kh * 11 + k]) : (unsigned short)0;
    }
    if (i < 32) {
        float s1 = g1[i] / sqrtf(v1[i] + 1e-5f);
        scsh[i]      = s1;
        scsh[32 + i] = b1[i] * s1 + be1[i] - m1[i] * s1;
        float s2 = g2[i] / sqrtf(v2[i] + 1e-5f);
        scsh[64 + i] = s2;
        scsh[96 + i] = b2[i] * s2 + be2[i] - m2[i] * s2;
        int l1 = (lens[i] - 1) / 2 + 1;
        if (l1 > W1_) l1 = W1_;
        lens1[i] = l1;
        out_lens[i] = (float)l1;
    }
}

// ---------------------------------------------------------------------------
// Conv1 MFMA: A (41 KB wf1) in LDS, shared by a 512-thread block (8 waves)
// -> 2 blocks/CU = 16 waves/CU. B direct from global (L1-hot padded rows).
// Waves: 4 w-subtiles x 2 h-pairs; wave tile Nt=2 (64w) x Hb=2. acc=64 VGPR.
// Wave-level mask skip; no barriers in main loop.
// ---------------------------------------------------------------------------
__global__ __launch_bounds__(512, 4) void conv1_mfma(
    const unsigned short* __restrict__ xbf,  // [32][161][1048] padded bf16
    const unsigned short* __restrict__ wf1,
    const float* __restrict__ scsh,
    const int* __restrict__ lens1,
    unsigned short* __restrict__ xg)         // [32][81][512][32] bf16
{
    const int t     = threadIdx.x;
    const int lane  = t & 63;
    const int l31   = lane & 31;
    const int lhi   = lane >> 5;
    const int wv    = t >> 6;                // 0..7
    const int wsub  = (wv & 3) * 64;
    const int hpair = wv >> 2;               // 0..1
    const int Wl    = blockIdx.x * 256 + wsub;
    const int h0b   = blockIdx.y * 4;
    const int b     = blockIdx.z;

    __shared__ __align__(16) uint4 swf[41 * 64];   // 41,984 B

#pragma unroll
    for (int k = 0; k < 6; ++k) {
        int idx = t + k * 512;
        if (idx < 41 * 64) swf[idx] = ((const uint4*)wf1)[idx];
    }
    __syncthreads();

    const int l1 = lens1[b];

    v16f acc[2][2];                                // [nt][hl]
#pragma unroll
    for (int nt = 0; nt < 2; ++nt)
#pragma unroll
        for (int hl = 0; hl < 2; ++hl)
#pragma unroll
            for (int i = 0; i < 16; ++i) acc[nt][hl][i] = 0.f;

    if (Wl < l1) {                                 // wave-uniform mask skip
        const char* xrow0 = (const char*)(xbf + (size_t)b * (H_IN * XBF_ROW));
        const int boff = 4 * (Wl + l31) + 16 * lhi;

        for (int rr = 0; rr < 47; ++rr) {
            const int r = 2 * h0b - 20 + rr;
            if (r < 0 || r >= H_IN) continue;

            const int kh0 = rr - 4 * hpair;        // hl=0
            const int kh1 = kh0 - 2;               // hl=1
            const int hg0 = h0b + 2 * hpair;
            const bool av0 = ((unsigned)kh0 < 41u) && (hg0 < H1_);
            const bool av1 = ((unsigned)kh1 < 41u) && (hg0 + 1 < H1_);
            if (!av0 && !av1) continue;

            const char* rowb = xrow0 + (size_t)r * (XBF_ROW * 2);
            uint4 bu0 = *(const uint4*)(rowb + boff);
            uint4 bu1 = *(const uint4*)(rowb + boff + 128);
            v8bf bv0 = __builtin_bit_cast(v8bf, bu0);
            v8bf bv1 = __builtin_bit_cast(v8bf, bu1);

            if (av0) {
                v8bf a = __builtin_bit_cast(v8bf, swf[kh0 * 64 + lane]);
                acc[0][0] = __builtin_amdgcn_mfma_f32_32x32x16_bf16(a, bv0, acc[0][0], 0, 0, 0);
                acc[1][0] = __builtin_amdgcn_mfma_f32_32x32x16_bf16(a, bv1, acc[1][0], 0, 0, 0);
            }
            if (av1) {
                v8bf a = __builtin_bit_cast(v8bf, swf[kh1 * 64 + lane]);
                acc[0][1] = __builtin_amdgcn_mfma_f32_32x32x16_bf16(a, bv0, acc[0][1], 0, 0, 0);
                acc[1][1] = __builtin_amdgcn_mfma_f32_32x32x16_bf16(a, bv1, acc[1][1], 0, 0, 0);
            }
        }
    }

    // epilogue: BN + hardtanh + mask, write xg[b][h][w][c] bf16
#pragma unroll
    for (int nt = 0; nt < 2; ++nt) {
        const int w = Wl + nt * 32 + l31;
        const bool keep = (w < l1);
#pragma unroll
        for (int hl = 0; hl < 2; ++hl) {
            const int h = h0b + 2 * hpair + hl;
            if (h < H1_) {
                unsigned short* dp = xg + (((size_t)b * H1_ + h) * W1_ + w) * 32;
#pragma unroll
                for (int rq = 0; rq < 4; ++rq) {
                    unsigned int wd[2];
#pragma unroll
                    for (int d = 0; d < 2; ++d) {
                        int rg = rq * 4 + d * 2;
                        int oc = 8 * rq + 4 * lhi + d * 2;
                        float v0 = fminf(fmaxf(fmaf(acc[nt][hl][rg],     scsh[oc],     scsh[32 + oc]), 0.f), 20.f);
                        float v1 = fminf(fmaxf(fmaf(acc[nt][hl][rg + 1], scsh[oc + 1], scsh[33 + oc]), 0.f), 20.f);
                        if (!keep) { v0 = 0.f; v1 = 0.f; }
                        wd[d] = (unsigned int)f2bf(v0) | ((unsigned int)f2bf(v1) << 16);
                    }
                    uint2 u; u.x = wd[0]; u.y = wd[1];
                    *(uint2*)(dp + 8 * rq + 4 * lhi) = u;
                }
            }
        }
    }
}

// ---------------------------------------------------------------------------
// Conv2 MFMA: block = 4 waves ALL on one h-pair (w-split 4x64 -> 256w x 2h).
// Per rr only kh in {rr, rr-2}: 44 KB A-set, L1 broadcast across 4 waves.
// Wave tile Nt=2 x Hb=2, acc=64 VGPR. LDS: 266 slots x 80B, dbuf = 42.56 KB
// -> 3 blocks/CU = 12 waves/CU. Block-uniform mask-skip.
// ---------------------------------------------------------------------------
#define ROWB2 21280   // 266 * 80

__global__ __launch_bounds__(256, 3) void conv2_mfma(
    const unsigned short* __restrict__ xg,   // [32][81][512][32] bf16
    const unsigned short* __restrict__ wf2,  // frag-ordered
    const float* __restrict__ scsh,
    const int* __restrict__ lens1,
    float* __restrict__ out)                 // [32][32][41][512] fp32
{
    const int t    = threadIdx.x;
    const int lane = t & 63;
    const int l31  = lane & 31;
    const int lhi  = lane >> 5;
    const int wv   = t >> 6;                 // 0..3
    const int wsub = wv * 64;
    const int w0   = blockIdx.x * 256;
    const int h0   = blockIdx.y * 2;
    const int b    = blockIdx.z;

    __shared__ __align__(16) char sbuf[2 * ROWB2];

    const int l1 = lens1[b];
    const bool active = (w0 < l1);           // block-uniform

    v16f acc[2][2];                          // [nt][hl]
#pragma unroll
    for (int nt = 0; nt < 2; ++nt)
#pragma unroll
        for (int hl = 0; hl < 2; ++hl)
#pragma unroll
            for (int i = 0; i < 16; ++i) acc[nt][hl][i] = 0.f;

    if (active) {
        // staging: 1064 uint4 chunks (266 slots x 4); thread t covers
        // i = t + 256k, k=0..3 (all), k=4 for t<40.
        const int s0    = t >> 2;
        const int ck    = t & 3;
        const int gbase = w0 - 5 + s0;       // +64 per k
        const int lbase = s0 * 80 + ck * 16; // +5120 per k
        const int goff  = ck * 8;

        const unsigned short* xb = xg + (size_t)b * (H1_ * W1_ * 32);
        const int rbase = 2 * h0 - 10;

        if (rbase >= 0 && rbase < H1_) {
            const unsigned short* xr = xb + (size_t)rbase * (W1_ * 32);
#pragma unroll
            for (int k = 0; k < 5; ++k) {
                if (k < 4 || t < 40) {
                    int gw = gbase + 64 * k;
                    uint4 z = {0, 0, 0, 0};
                    if ((unsigned)gw < (unsigned)W1_) z = *(const uint4*)(xr + (size_t)gw * 32 + goff);
                    *(uint4*)(sbuf + lbase + k * 5120) = z;
                }
            }
        }
        __syncthreads();

        const int bro = (wsub + l31) * 80 + lhi * 16;   // + nt*2560 + kw*80 + ch*32

        for (int rr = 0; rr < 23; ++rr) {
            const int p  = rr & 1;
            const int rn = rbase + rr + 1;
            const bool sv = (rr < 22) && rn >= 0 && rn < H1_;

            uint4 z[5];
#pragma unroll
            for (int k = 0; k < 5; ++k) { z[k].x = 0; z[k].y = 0; z[k].z = 0; z[k].w = 0; }
            if (sv) {
                const unsigned short* xr = xb + (size_t)rn * (W1_ * 32);
#pragma unroll
                for (int k = 0; k < 5; ++k) {
                    if (k < 4 || t < 40) {
                        int gw = gbase + 64 * k;
                        if ((unsigned)gw < (unsigned)W1_) z[k] = *(const uint4*)(xr + (size_t)gw * 32 + goff);
                    }
                }
            }

            const int r = rbase + rr;
            if (r >= 0 && r < H1_) {
                const int kh0 = rr;              // -> h0
                const int kh1 = rr - 2;          // -> h0+1
                const bool av0 = ((unsigned)kh0 < 21u) && (h0 < H2_);
                const bool av1 = ((unsigned)kh1 < 21u) && (h0 + 1 < H2_);
                const char* bb = sbuf + p * ROWB2 + bro;
                const char* wb = (const char*)wf2;
#pragma unroll
                for (int kw = 0; kw < 11; ++kw) {
#pragma unroll
                    for (int ch = 0; ch < 2; ++ch) {
                        uint4 b0u = *(const uint4*)(bb + kw * 80 + ch * 32);
                        uint4 b1u = *(const uint4*)(bb + 2560 + kw * 80 + ch * 32);
                        v8bf bv0 = __builtin_bit_cast(v8bf, b0u);
                        v8bf bv1 = __builtin_bit_cast(v8bf, b1u);
                        if (av0) {
                            uint4 au = *(const uint4*)(wb + (size_t)((kh0 * 11 + kw) * 2 + ch) * 1024 + lane * 16);
                            v8bf a = __builtin_bit_cast(v8bf, au);
                            acc[0][0] = __builtin_amdgcn_mfma_f32_32x32x16_bf16(a, bv0, acc[0][0], 0, 0, 0);
                            acc[1][0] = __builtin_amdgcn_mfma_f32_32x32x16_bf16(a, bv1, acc[1][0], 0, 0, 0);
                        }
                        if (av1) {
                            uint4 au = *(const uint4*)(wb + (size_t)((kh1 * 11 + kw) * 2 + ch) * 1024 + lane * 16);
                            v8bf a = __builtin_bit_cast(v8bf, au);
                            acc[0][1] = __builtin_amdgcn_mfma_f32_32x32x16_bf16(a, bv0, acc[0][1], 0, 0, 0);
                            acc[1][1] = __builtin_amdgcn_mfma_f32_32x32x16_bf16(a, bv1, acc[1][1], 0, 0, 0);
                        }
                    }
                }
            }

            if (sv) {
                char* wbuf = sbuf + (p ^ 1) * ROWB2;
#pragma unroll
                for (int k = 0; k < 5; ++k)
                    if (k < 4 || t < 40) *(uint4*)(wbuf + lbase + k * 5120) = z[k];
            }
            __syncthreads();
        }
    }

    // epilogue (all blocks; inactive ones write zeros via keep-mask)
#pragma unroll
    for (int nt = 0; nt < 2; ++nt) {
        const int w = w0 + wsub + nt * 32 + l31;
        const bool keep = (w < l1);
#pragma unroll
        for (int hl = 0; hl < 2; ++hl) {
            const int h = h0 + hl;
            if (h < H2_) {
#pragma unroll
                for (int reg = 0; reg < 16; ++reg) {
                    int oc = (reg & 3) + 8 * (reg >> 2) + 4 * lhi;
                    float v = fmaf(acc[nt][hl][reg], scsh[64 + oc], scsh[96 + oc]);
                    v = fminf(fmaxf(v, 0.f), 20.f);
                    out[(((size_t)b * C2_ + oc) * H2_ + h) * W2_ + w] = keep ? v : 0.f;
                }
            }
        }
    }
}

// ---------------------------------------------------------------------------
extern "C" void kernel_launch(void* const* d_in, const int* in_sizes, int n_in,
                              void* d_out, int out_size, void* d_ws, size_t ws_size,
                              hipStream_t stream) {
    const float* inputs = (const float*)d_in[0];
    const int*   slen   = (const int*)d_in[1];
    const float* w1 = (const float*)d_in[2];
    const float* b1 = (const float*)d_in[3];
    const float* g1 = (const float*)d_in[4];
    const float* be1 = (const float*)d_in[5];
    const float* m1 = (const float*)d_in[6];
    const float* v1 = (const float*)d_in[7];
    const float* w2 = (const float*)d_in[8];
    const float* b2 = (const float*)d_in[9];
    const float* g2 = (const float*)d_in[10];
    const float* be2 = (const float*)d_in[11];
    const float* m2 = (const float*)d_in[12];
    const float* v2 = (const float*)d_in[13];

    char* ws = (char*)d_ws;
    unsigned short* wf2  = (unsigned short*)(ws + WF2_B);
    unsigned short* wf1  = (unsigned short*)(ws + WF1_B);
    float*          scsh = (float*)(ws + SCSH_B);
    int*            lens1 = (int*)(ws + LENS1_B);
    unsigned short* xbf  = (unsigned short*)(ws + XBF_B);
    unsigned short* xg   = (unsigned short*)(ws + XG_B);

    float* out_x    = (float*)d_out;
    float* out_lens = out_x + OUT_X_SZ;

    hipLaunchKernelGGL(prep_kernel, dim3(1024), dim3(256), 0, stream,
                       inputs, w1, b1, g1, be1, m1, v1, w2, b2, g2, be2, m2, v2,
                       slen, wf1, wf2, xbf, scsh, lens1, out_lens);

    hipLaunchKernelGGL(conv1_mfma, dim3(2, 21, B_), dim3(512), 0, stream,
                       xbf, wf1, scsh, lens1, xg);

    hipLaunchKernelGGL(conv2_mfma, dim3(2, 21, B_), dim3(256), 0, stream,
                       xg, wf2, scsh, lens1, out_x);
}